// Round 1
// baseline (450.483 us; speedup 1.0000x reference)
//
#include <hip/hip_runtime.h>

// PerturbedTopK: x(32,2048) f32, noise(32,500,2048) f32.
// out = [indicators (32,128,2048) f32, idx (32,500,128) as f32], concatenated.
//
// One wave (64 lanes) per (b,n) row. Lane owns 32 contiguous elements in
// registers as monotone-orderable uint32 keys. Exact kth-largest via 32-pass
// MSB->LSB bitwise radix select (wave butterfly reduce per pass). Emission in
// index order via packed gt|eq wave scan -> ascending sorted idx for free.

constexpr int B_     = 32;
constexpr int D_     = 2048;
constexpr int NS_    = 500;
constexpr int TOPK_  = 128;
constexpr float SIGMA_ = 0.05f;
constexpr int LANES_ = 64;
constexpr int PER_LANE_ = D_ / LANES_;       // 32
constexpr int WAVES_PER_BLOCK_ = 4;          // 4 rows per 256-thread block

__device__ __forceinline__ uint32_t order_key(float f) {
  uint32_t u = __float_as_uint(f);
  // monotone increasing map: larger float -> larger uint
  return (u & 0x80000000u) ? ~u : (u | 0x80000000u);
}

__global__ __launch_bounds__(256) void ptk_select(
    const float* __restrict__ x, const float* __restrict__ noise,
    float* __restrict__ indicators, float* __restrict__ out_idx) {
  const int lane = threadIdx.x & 63;
  const int wave = threadIdx.x >> 6;
  const int row  = blockIdx.x * WAVES_PER_BLOCK_ + wave;   // 0..15999
  const int b = row / NS_;
  const int n = row - b * NS_;

  const float* __restrict__ xr = x + (size_t)b * D_;
  const float* __restrict__ nr = noise + ((size_t)b * NS_ + n) * D_;
  const int base_i = lane * PER_LANE_;

  uint32_t keys[PER_LANE_];
#pragma unroll
  for (int j = 0; j < PER_LANE_; j += 4) {
    const float4 nv = *reinterpret_cast<const float4*>(nr + base_i + j);
    const float4 xv = *reinterpret_cast<const float4*>(xr + base_i + j);
    keys[j + 0] = order_key(fmaf(SIGMA_, nv.x, xv.x));
    keys[j + 1] = order_key(fmaf(SIGMA_, nv.y, xv.y));
    keys[j + 2] = order_key(fmaf(SIGMA_, nv.z, xv.z));
    keys[j + 3] = order_key(fmaf(SIGMA_, nv.w, xv.w));
  }

  // --- exact 128th-largest key: bitwise radix select, MSB -> LSB ---
  uint32_t prefix = 0;
  int k = TOPK_;
#pragma unroll 1
  for (int bit = 31; bit >= 0; --bit) {
    const uint32_t want = (prefix >> bit) | 1u;
    int c = 0;
#pragma unroll
    for (int j = 0; j < PER_LANE_; ++j) c += ((keys[j] >> bit) == want) ? 1 : 0;
#pragma unroll
    for (int off = 32; off >= 1; off >>= 1) c += __shfl_xor(c, off);
    if (c >= k) prefix |= (1u << bit);
    else        k -= c;
  }
  const int r = k;  // number of keys == prefix to take (lowest index first)

  // --- per-lane counts & wave exclusive scan (gt in low16, eq in high16) ---
  int gt = 0, eq = 0;
#pragma unroll
  for (int j = 0; j < PER_LANE_; ++j) {
    gt += (keys[j] > prefix) ? 1 : 0;
    eq += (keys[j] == prefix) ? 1 : 0;
  }
  uint32_t incl = (uint32_t)gt | ((uint32_t)eq << 16);
#pragma unroll
  for (int off = 1; off < 64; off <<= 1) {
    uint32_t y = __shfl_up(incl, (unsigned)off);
    if (lane >= off) incl += y;
  }
  const int gt_base = (int)(incl & 0xFFFFu) - gt;
  const int eq_base = (int)(incl >> 16) - eq;

  // selected at smaller index = all strictly-greater before us + equals taken before us
  int pos = gt_base + min(eq_base, r);
  int eq_seen = eq_base;

  float* __restrict__ ind_b   = indicators + (size_t)b * TOPK_ * D_;
  float* __restrict__ idx_row = out_idx + (size_t)row * TOPK_;
  const float inc = 1.0f / (float)NS_;

#pragma unroll
  for (int j = 0; j < PER_LANE_; ++j) {
    const uint32_t kj = keys[j];
    bool s = false;
    if (kj > prefix) {
      s = true;
    } else if (kj == prefix) {
      s = (eq_seen < r);
      eq_seen++;
    }
    if (s) {
      const int i = base_i + j;
      idx_row[pos] = (float)i;
      atomicAdd(ind_b + (size_t)pos * D_ + i, inc);
      pos++;
    }
  }
}

extern "C" void kernel_launch(void* const* d_in, const int* in_sizes, int n_in,
                              void* d_out, int out_size, void* d_ws, size_t ws_size,
                              hipStream_t stream) {
  const float* x     = (const float*)d_in[0];
  const float* noise = (const float*)d_in[1];
  float* indicators  = (float*)d_out;
  float* out_idx     = (float*)d_out + (size_t)B_ * TOPK_ * D_;

  // zero the scatter-accumulated indicators region (d_out is poisoned 0xAA)
  hipMemsetAsync(d_out, 0, (size_t)B_ * TOPK_ * D_ * sizeof(float), stream);

  const int rows = B_ * NS_;                       // 16000
  dim3 grid(rows / WAVES_PER_BLOCK_), block(256);  // 4000 x 256
  hipLaunchKernelGGL(ptk_select, grid, block, 0, stream,
                     x, noise, indicators, out_idx);
}